// Round 9
// baseline (341.905 us; speedup 1.0000x reference)
//
#include <hip/hip_runtime.h>
#include <stdint.h>

#define OBS_LEN 12
#define KS 20
#define BB 2048
#define HD 128
#define MIDD 256
#define NCQ 2

// d_ws layout (bf16 elems): fragment-ordered weight copies
#define WSW_OFF  0          // whh  [8w][4gate][4q][64l][8]  = 65536
#define WSM0_OFF 65536      // mw0  [8w][2ct][4q][64l][8]    = 32768
#define WSM1_OFF 98304      // mw1  [8w][8q][64l][8]         = 32768
#define WSO_OFF  131072     // oww  [4q][64l][8]             = 2048
#define WSX_OFF  133120     // wih/bias [8w][4gate][16ln][8] = 4096
#define WS_ELEMS 137216     // * 2 B = 274432 bytes

using f32x4  = __attribute__((ext_vector_type(4))) float;
using bf16x8 = __attribute__((ext_vector_type(8))) short;

static __device__ __forceinline__ short f2bf(float f){
  return __builtin_bit_cast(short, (__bf16)f);   // RNE convert
}
static __device__ __forceinline__ uint32_t pack2(float a, float b){
  return (uint32_t)(uint16_t)f2bf(a) | ((uint32_t)(uint16_t)f2bf(b) << 16);
}
static __device__ __forceinline__ float hsig(float x){
  return fminf(fmaxf(fmaf(x, 0.16666666666666666f, 0.5f), 0.f), 1.f);
}
static __device__ __forceinline__ float clip1(float x){
  return fminf(fmaxf(x, -1.f), 1.f);
}
static __device__ __forceinline__ f32x4 mm(bf16x8 a, bf16x8 b, f32x4 c){
  return __builtin_amdgcn_mfma_f32_16x16x32_bf16(a, b, c, 0, 0, 0);
}
static __device__ __forceinline__ bf16x8 ldh(const uint16_t* buf, int row, int q, int p){
  return *reinterpret_cast<const bf16x8*>(&buf[(row*HD + q*32 + p*8) ^ ((row&7)*8)]);
}
static __device__ __forceinline__ bf16x8 lda(const uint16_t* buf, int row, int q, int p){
  return *reinterpret_cast<const bf16x8*>(&buf[(row*MIDD + q*32 + p*8) ^ ((row&7)*8)]);
}

// ---------------- prep: reorder weights into MFMA fragment order ----------------
__global__ void CRMF_prep_kernel(const float* __restrict__ mw0,
                                 const float* __restrict__ mw1,
                                 const float* __restrict__ whh,
                                 const float* __restrict__ oww,
                                 const float* __restrict__ wih,
                                 const float* __restrict__ bih,
                                 const float* __restrict__ bhh,
                                 uint16_t* __restrict__ ws)
{
  int f = blockIdx.x*256 + threadIdx.x;
  if (f >= 17152) return;
  bf16x8 out = {0,0,0,0,0,0,0,0};
  int dst;
  if (f < 8192){                       // whh frags
    int l=f&63, q=(f>>6)&3, gate=(f>>8)&3, w=f>>10;
    int col = gate*128 + w*16 + (l&15);
    const float* s = whh + col*HD + q*32 + ((l>>4)&3)*8;
    #pragma unroll
    for (int j=0;j<8;++j) out[j] = f2bf(s[j]);
    dst = WSW_OFF + f*8;
  } else if (f < 12288){               // mw0 frags
    int ff=f-8192; int l=ff&63, q=(ff>>6)&3, ct=(ff>>8)&1, w=ff>>9;
    int col = w*32 + ct*16 + (l&15);
    int r0 = q*32 + ((l>>4)&3)*8;
    #pragma unroll
    for (int j=0;j<8;++j) out[j] = f2bf(mw0[(r0+j)*MIDD + col]);
    dst = WSM0_OFF + ff*8;
  } else if (f < 16384){               // mw1 frags
    int ff=f-12288; int l=ff&63, q=(ff>>6)&7, w=ff>>9;
    int col = w*16 + (l&15);
    int r0 = q*32 + ((l>>4)&3)*8;
    #pragma unroll
    for (int j=0;j<8;++j) out[j] = f2bf(mw1[(r0+j)*HD + col]);
    dst = WSM1_OFF + ff*8;
  } else if (f < 16640){               // oww frags
    int ff=f-16384; int l=ff&63, q=ff>>6;
    int lnn=l&15; int r0 = q*32 + ((l>>4)&3)*8;
    #pragma unroll
    for (int j=0;j<8;++j) out[j] = (lnn<NCQ) ? f2bf(oww[(r0+j)*NCQ + lnn]) : (short)0;
    dst = WSO_OFF + ff*8;
  } else {                             // x-projection frags (wih cols + bias)
    int e=f-16640; int w=e>>6, gate=(e>>4)&3, lnn=e&15;
    int col = gate*128 + w*16 + lnn;
    out[0] = f2bf(wih[col*2]);
    out[1] = f2bf(wih[col*2+1]);
    out[2] = f2bf(bih[col] + bhh[col]);
    dst = WSX_OFF + e*8;
  }
  *reinterpret_cast<bf16x8*>(&ws[dst]) = out;
}

// ---------------- main kernel: 512 thr, slim waves, 2 blocks/CU ----------------
template<bool FWS>
__global__ __launch_bounds__(512, 4)
void CRMF_35296041239144_kernel(
    const float* __restrict__ obs,  const float* __restrict__ pred,
    const float* __restrict__ mw0,  const float* __restrict__ mb0,
    const float* __restrict__ mw1,  const float* __restrict__ mb1,
    const float* __restrict__ wih,  const float* __restrict__ whh,
    const float* __restrict__ bih,  const float* __restrict__ bhh,
    const float* __restrict__ oww,  const float* __restrict__ obb,
    const uint16_t* __restrict__ ws,
    float* __restrict__ outp)
{
  __shared__ __align__(16) uint16_t hbuf[2][32*HD];   // 16 KB, double buffered
  __shared__ __align__(16) uint16_t abuf[32*MIDD];    // 16 KB MLP activations
  __shared__ __align__(16) uint16_t ofrag[2][4*64*8]; // 8 KB out_w frags (x2 anti-LICM)
  __shared__ __align__(16) uint16_t wfx[2][512*8];    // 16 KB x-proj frags (x2 anti-LICM)
  __shared__ float2 xbuf[OBS_LEN][32];                // 3 KB shifted obs

  const int tid = threadIdx.x;
  const int w   = tid >> 6;          // wave 0..7
  const int l   = tid & 63;
  const int p   = (tid >> 4) & 3;
  const int ln  = tid & 15;
  const int wofs = w * 16;           // wave's 16-hd slice
  const bool w7 = (w == 7);

  const int b  = blockIdx.x;         // 512 blocks, 2 per CU
  const int b0 = (b & 63) * 32;
  const int j  = b >> 6;             // 0..7
  const int nch = (j < 4) ? 3 : 2;   // 64*(4*3 + 4*2) = 1280 chunks

  // ---- shifted obs ----
  if (tid < OBS_LEN*32){
    int t = tid >> 5, cc = tid & 31;
    int st = t ? (t-1) : 0;
    const float* pp = obs + ((size_t)st*BB + b0 + cc)*3;
    xbuf[t][cc] = make_float2(pp[0], pp[1]);
  }
  // ---- out_w fragments -> LDS (both parity copies) ----
  if (tid < 256){
    bf16x8 wf;
    if constexpr (FWS){
      wf = *reinterpret_cast<const bf16x8*>(&ws[WSO_OFF + tid*8]);
    } else {
      int q = tid >> 6, ll = tid & 63;
      int lln = ll & 15, pp2 = (ll >> 4) & 3;
      #pragma unroll
      for (int jj=0; jj<8; ++jj)
        wf[jj] = (lln < NCQ) ? f2bf(oww[(q*32+pp2*8+jj)*NCQ + lln]) : (short)0;
    }
    *reinterpret_cast<bf16x8*>(&ofrag[0][tid*8]) = wf;
    *reinterpret_cast<bf16x8*>(&ofrag[1][tid*8]) = wf;
  }
  // ---- x-projection fragments -> LDS (both parity copies) ----
  if (tid < 512){
    bf16x8 wf;
    if constexpr (FWS){
      wf = *reinterpret_cast<const bf16x8*>(&ws[WSX_OFF + tid*8]);
    } else {
      int ww=tid>>6, gate=(tid>>4)&3, lnn=tid&15;
      int col = gate*128 + ww*16 + lnn;
      bf16x8 z = {0,0,0,0,0,0,0,0};
      wf = z;
      wf[0] = f2bf(wih[col*2]);
      wf[1] = f2bf(wih[col*2+1]);
      wf[2] = f2bf(bih[col] + bhh[col]);
    }
    *reinterpret_cast<bf16x8*>(&wfx[0][tid*8]) = wf;
    *reinterpret_cast<bf16x8*>(&wfx[1][tid*8]) = wf;
  }
  const float obv = (ln < NCQ) ? obb[ln] : 0.f;

  // ---- chunks ----
  #pragma unroll 1
  for (int i=0; i<nch; ++i){
    const int kk = (j < 4) ? (j + 4*i) : (12 + (j-4) + 4*i);

    __syncthreads();                 // staging / previous chunk readers done
    // stage h0 -> hbuf[0]
    {
      const float* src = pred + ((size_t)(kk*BB + b0))*HD;
      #pragma unroll
      for (int it=0; it<2; ++it){
        int u = tid + it*512;
        int row = u >> 5, c4 = (u & 31)*4;
        float4 v = *reinterpret_cast<const float4*>(src + row*HD + c4);
        int e = (row*HD + c4) ^ ((row&7)*8);
        *reinterpret_cast<uint32_t*>(&hbuf[0][e])   = pack2(v.x, v.y);
        *reinterpret_cast<uint32_t*>(&hbuf[0][e+2]) = pack2(v.z, v.w);
      }
    }
    __syncthreads();

    // ---- MLP GEMM1: [32,128] @ map_w0 -> [32,256]; 32 cols/wave ----
    {
      f32x4 acc1[2][2];
      #pragma unroll
      for (int ct=0; ct<2; ++ct){
        float mb = mb0[w*32 + ct*16 + ln];
        f32x4 v = {mb,mb,mb,mb};
        acc1[0][ct]=v; acc1[1][ct]=v;
      }
      #pragma unroll
      for (int q=0; q<4; ++q){
        bf16x8 af0 = ldh(hbuf[0], ln, q, p), af1 = ldh(hbuf[0], 16+ln, q, p);
        #pragma unroll
        for (int ct=0; ct<2; ++ct){
          bf16x8 wf;
          if constexpr (FWS){
            wf = *reinterpret_cast<const bf16x8*>(&ws[WSM0_OFF + (((w*2+ct)*4+q)*64 + l)*8]);
          } else {
            #pragma unroll
            for (int jj=0; jj<8; ++jj)
              wf[jj] = f2bf(mw0[(q*32+p*8+jj)*MIDD + (w*32 + ct*16 + ln)]);
          }
          acc1[0][ct] = mm(af0, wf, acc1[0][ct]);
          acc1[1][ct] = mm(af1, wf, acc1[1][ct]);
        }
      }
      #pragma unroll
      for (int rt=0; rt<2; ++rt)
      #pragma unroll
      for (int ct=0; ct<2; ++ct)
      #pragma unroll
      for (int r=0; r<4; ++r){
        float v = acc1[rt][ct][r];
        v = (v>0.f)? v : 0.01f*v;
        int row = rt*16 + p*4 + r;
        abuf[(row*MIDD + w*32 + ct*16 + ln) ^ ((row&7)*8)] = (uint16_t)f2bf(v);
      }
    }
    __syncthreads();

    // ---- MLP GEMM2: [32,256] @ map_w1 -> h_init; 16 cols/wave ----
    float c_[2][4];
    {
      f32x4 acc2[2];
      float mb = mb1[wofs + ln];
      f32x4 v = {mb,mb,mb,mb};
      acc2[0]=v; acc2[1]=v;
      #pragma unroll
      for (int q=0; q<8; ++q){
        bf16x8 af0 = lda(abuf, ln, q, p), af1 = lda(abuf, 16+ln, q, p);
        bf16x8 wf;
        if constexpr (FWS){
          wf = *reinterpret_cast<const bf16x8*>(&ws[WSM1_OFF + ((w*8+q)*64 + l)*8]);
        } else {
          #pragma unroll
          for (int jj=0; jj<8; ++jj)
            wf[jj] = f2bf(mw1[(q*32+p*8+jj)*HD + wofs + ln]);
        }
        acc2[0] = mm(af0, wf, acc2[0]);
        acc2[1] = mm(af1, wf, acc2[1]);
      }
      #pragma unroll
      for (int rt=0; rt<2; ++rt)
      #pragma unroll
      for (int r=0; r<4; ++r){
        int row = rt*16 + p*4 + r;
        hbuf[0][(row*HD + wofs + ln) ^ ((row&7)*8)] = (uint16_t)f2bf(acc2[rt][r]);
        c_[rt][r] = 0.f;
      }
    }

    // ---- w_hh fragments -> registers (64 VGPR), coalesced from ws ----
    bf16x8 wfrag[4][4];
    #pragma unroll
    for (int gate=0; gate<4; ++gate){
      #pragma unroll
      for (int q=0; q<4; ++q){
        if constexpr (FWS){
          wfrag[gate][q] = *reinterpret_cast<const bf16x8*>(
              &ws[WSW_OFF + (((w*4+gate)*4+q)*64 + l)*8]);
        } else {
          int col = gate*128 + wofs + ln;
          const float* s = whh + col*HD + q*32 + p*8;
          float4 f0 = *reinterpret_cast<const float4*>(s);
          float4 f1 = *reinterpret_cast<const float4*>(s+4);
          bf16x8 wf;
          wf[0]=f2bf(f0.x); wf[1]=f2bf(f0.y); wf[2]=f2bf(f0.z); wf[3]=f2bf(f0.w);
          wf[4]=f2bf(f1.x); wf[5]=f2bf(f1.y); wf[6]=f2bf(f1.z); wf[7]=f2bf(f1.w);
          wfrag[gate][q] = wf;
        }
      }
    }
    __syncthreads();                 // h_init visible

    // ---- 12 recurrent steps: ONE barrier/step, x-fold via 5th K-quad ----
    #pragma unroll 1
    for (int t=0; t<OBS_LEN; ++t){
      const int cur = t & 1, nxt = cur ^ 1;
      // synthetic A fragments: {x0, x1, 1, 0...} in p==0 lanes
      bf16x8 xq0 = {0,0,0,0,0,0,0,0}, xq1 = xq0;
      if (p == 0){
        float2 xv0 = xbuf[t][ln];
        float2 xv1 = xbuf[t][16+ln];
        xq0[0]=f2bf(xv0.x); xq0[1]=f2bf(xv0.y); xq0[2]=(short)0x3F80;
        xq1[0]=f2bf(xv1.x); xq1[1]=f2bf(xv1.y); xq1[2]=(short)0x3F80;
      }
      f32x4 acc[2][4];
      const f32x4 zed = {0.f,0.f,0.f,0.f};
      #pragma unroll
      for (int gate=0; gate<4; ++gate){
        bf16x8 bx = {0,0,0,0,0,0,0,0};
        if (p == 0)
          bx = *reinterpret_cast<const bf16x8*>(&wfx[cur][((w*4+gate)*16 + ln)*8]);
        acc[0][gate] = mm(xq0, bx, zed);
        acc[1][gate] = mm(xq1, bx, zed);
      }
      f32x4 a8[2];
      if (w7 && t>0){ f32x4 v={obv,obv,obv,obv}; a8[0]=v; a8[1]=v; }
      #pragma unroll
      for (int q=0; q<4; ++q){
        bf16x8 af0 = ldh(hbuf[cur], ln, q, p), af1 = ldh(hbuf[cur], 16+ln, q, p);
        #pragma unroll
        for (int gate=0; gate<4; ++gate){
          acc[0][gate] = mm(af0, wfrag[gate][q], acc[0][gate]);
          acc[1][gate] = mm(af1, wfrag[gate][q], acc[1][gate]);
        }
        if (w7 && t>0){
          bf16x8 of = *reinterpret_cast<const bf16x8*>(&ofrag[cur][(q*64 + l)*8]);
          a8[0] = mm(af0, of, a8[0]);
          a8[1] = mm(af1, of, a8[1]);
        }
      }
      if (w7 && t>0 && ln<NCQ){
        #pragma unroll
        for (int rt=0; rt<2; ++rt)
        #pragma unroll
        for (int r=0; r<4; ++r){
          int cell = rt*16 + p*4 + r;
          outp[(((size_t)(t-1)*KS + kk)*BB + b0 + cell)*NCQ + ln] = a8[rt][r];
        }
      }
      #pragma unroll
      for (int rt=0; rt<2; ++rt)
      #pragma unroll
      for (int r=0; r<4; ++r){
        float iv = hsig(acc[rt][0][r]);
        float fv = hsig(acc[rt][1][r]);
        float gv = clip1(acc[rt][2][r]);
        float ov = hsig(acc[rt][3][r]);
        float cv = fmaf(fv, c_[rt][r], iv*gv);
        c_[rt][r] = cv;
        int row = rt*16 + p*4 + r;
        hbuf[nxt][(row*HD + wofs + ln) ^ ((row&7)*8)] = (uint16_t)f2bf(ov * clip1(cv));
      }
      __syncthreads();               // h[nxt] visible for next step's reads
    }

    // ---- final out_11 = h_12 @ out_w + out_b (final h in hbuf[0]) ----
    if (w7){
      f32x4 o0 = {obv,obv,obv,obv}, o1 = o0;
      #pragma unroll
      for (int q=0; q<4; ++q){
        bf16x8 af0 = ldh(hbuf[0], ln, q, p), af1 = ldh(hbuf[0], 16+ln, q, p);
        bf16x8 of = *reinterpret_cast<const bf16x8*>(&ofrag[0][(q*64 + l)*8]);
        o0 = mm(af0, of, o0);
        o1 = mm(af1, of, o1);
      }
      if (ln < NCQ){
        #pragma unroll
        for (int r=0; r<4; ++r){
          outp[(((size_t)11*KS + kk)*BB + b0 +      (p*4+r))*NCQ + ln] = o0[r];
          outp[(((size_t)11*KS + kk)*BB + b0 + 16 + (p*4+r))*NCQ + ln] = o1[r];
        }
      }
    }
  }
}

extern "C" void kernel_launch(void* const* d_in, const int* in_sizes, int n_in,
                              void* d_out, int out_size, void* d_ws, size_t ws_size,
                              hipStream_t stream) {
  (void)in_sizes; (void)n_in; (void)out_size;
  const float* obs  = (const float*)d_in[0];
  const float* pred = (const float*)d_in[1];
  const float* mw0  = (const float*)d_in[2];
  const float* mb0  = (const float*)d_in[3];
  const float* mw1  = (const float*)d_in[4];
  const float* mb1  = (const float*)d_in[5];
  const float* wih  = (const float*)d_in[6];
  const float* whh  = (const float*)d_in[7];
  const float* bih  = (const float*)d_in[8];
  const float* bhh  = (const float*)d_in[9];
  const float* oww  = (const float*)d_in[10];
  const float* obb  = (const float*)d_in[11];
  float* outp = (float*)d_out;

  if (ws_size >= (size_t)WS_ELEMS * sizeof(uint16_t)){
    uint16_t* ws = (uint16_t*)d_ws;
    CRMF_prep_kernel<<<dim3(67), dim3(256), 0, stream>>>(mw0, mw1, whh, oww,
                                                         wih, bih, bhh, ws);
    CRMF_35296041239144_kernel<true><<<dim3(512), dim3(512), 0, stream>>>(
        obs, pred, mw0, mb0, mw1, mb1, wih, whh, bih, bhh, oww, obb,
        (const uint16_t*)ws, outp);
  } else {
    CRMF_35296041239144_kernel<false><<<dim3(512), dim3(512), 0, stream>>>(
        obs, pred, mw0, mb0, mw1, mb1, wih, whh, bih, bhh, oww, obb,
        (const uint16_t*)nullptr, outp);
  }
}

// Round 10
// 176.950 us; speedup vs baseline: 1.9322x; 1.9322x over previous
//
#include <hip/hip_runtime.h>
#include <stdint.h>

#define OBS_LEN 12
#define KS 20
#define BB 2048
#define HD 128
#define MIDD 256
#define NCQ 2

// d_ws layout (bf16 elems): fragment-ordered weight copies
#define WSW_OFF  0          // whh  [8w][4gate][4q][64l][8]  = 65536
#define WSM0_OFF 65536      // mw0  [8w][2ct][4q][64l][8]    = 32768
#define WSM1_OFF 98304      // mw1  [8w][8q][64l][8]         = 32768
#define WSO_OFF  131072     // oww  [4q][64l][8]             = 2048
#define WS_ELEMS 133120     // * 2 B = 266240 bytes

using f32x4  = __attribute__((ext_vector_type(4))) float;
using bf16x8 = __attribute__((ext_vector_type(8))) short;

static __device__ __forceinline__ short f2bf(float f){
  return __builtin_bit_cast(short, (__bf16)f);   // RNE convert
}
static __device__ __forceinline__ uint32_t pack2(float a, float b){
  return (uint32_t)(uint16_t)f2bf(a) | ((uint32_t)(uint16_t)f2bf(b) << 16);
}
static __device__ __forceinline__ float hsig(float x){
  return fminf(fmaxf(fmaf(x, 0.16666666666666666f, 0.5f), 0.f), 1.f);
}
static __device__ __forceinline__ float clip1(float x){
  return fminf(fmaxf(x, -1.f), 1.f);
}
static __device__ __forceinline__ f32x4 mm(bf16x8 a, bf16x8 b, f32x4 c){
  return __builtin_amdgcn_mfma_f32_16x16x32_bf16(a, b, c, 0, 0, 0);
}
static __device__ __forceinline__ bf16x8 ldh(const uint16_t* buf, int row, int q, int p){
  return *reinterpret_cast<const bf16x8*>(&buf[(row*HD + q*32 + p*8) ^ ((row&7)*8)]);
}
static __device__ __forceinline__ bf16x8 lda(const uint16_t* buf, int row, int q, int p){
  return *reinterpret_cast<const bf16x8*>(&buf[(row*MIDD + q*32 + p*8) ^ ((row&7)*8)]);
}

// ---------------- prep: reorder weights into MFMA fragment order ----------------
__global__ void CRMF_prep_kernel(const float* __restrict__ mw0,
                                 const float* __restrict__ mw1,
                                 const float* __restrict__ whh,
                                 const float* __restrict__ oww,
                                 uint16_t* __restrict__ ws)
{
  int f = blockIdx.x*256 + threadIdx.x;
  if (f >= 16640) return;
  bf16x8 out;
  int dst;
  if (f < 8192){                       // whh frags
    int l=f&63, q=(f>>6)&3, gate=(f>>8)&3, w=f>>10;
    int col = gate*128 + w*16 + (l&15);
    const float* s = whh + col*HD + q*32 + ((l>>4)&3)*8;
    #pragma unroll
    for (int j=0;j<8;++j) out[j] = f2bf(s[j]);
    dst = WSW_OFF + f*8;
  } else if (f < 12288){               // mw0 frags
    int ff=f-8192; int l=ff&63, q=(ff>>6)&3, ct=(ff>>8)&1, w=ff>>9;
    int col = w*32 + ct*16 + (l&15);
    int r0 = q*32 + ((l>>4)&3)*8;
    #pragma unroll
    for (int j=0;j<8;++j) out[j] = f2bf(mw0[(r0+j)*MIDD + col]);
    dst = WSM0_OFF + ff*8;
  } else if (f < 16384){               // mw1 frags
    int ff=f-12288; int l=ff&63, q=(ff>>6)&7, w=ff>>9;
    int col = w*16 + (l&15);
    int r0 = q*32 + ((l>>4)&3)*8;
    #pragma unroll
    for (int j=0;j<8;++j) out[j] = f2bf(mw1[(r0+j)*HD + col]);
    dst = WSM1_OFF + ff*8;
  } else {                             // oww frags
    int ff=f-16384; int l=ff&63, q=ff>>6;
    int lnn=l&15; int r0 = q*32 + ((l>>4)&3)*8;
    #pragma unroll
    for (int j=0;j<8;++j) out[j] = (lnn<NCQ) ? f2bf(oww[(r0+j)*NCQ + lnn]) : (short)0;
    dst = WSO_OFF + ff*8;
  }
  *reinterpret_cast<bf16x8*>(&ws[dst]) = out;
}

// ---------------- main kernel: R5 structure + FWS weights + batched out ----------------
template<bool FWS>
__global__ __launch_bounds__(512, 2)
void CRMF_35296041239144_kernel(
    const float* __restrict__ obs,  const float* __restrict__ pred,
    const float* __restrict__ mw0,  const float* __restrict__ mb0,
    const float* __restrict__ mw1,  const float* __restrict__ mb1,
    const float* __restrict__ wih,  const float* __restrict__ whh,
    const float* __restrict__ bih,  const float* __restrict__ bhh,
    const float* __restrict__ oww,  const float* __restrict__ obb,
    const uint16_t* __restrict__ ws,
    float* __restrict__ outp)
{
  __shared__ __align__(16) uint16_t hbuf[2][32*HD];  // 16 KB h, double buffered
  __shared__ __align__(16) uint16_t abuf[32*MIDD];   // 16 KB MLP activations
  __shared__ __align__(16) uint16_t ofrag[4*64*8];   // 4 KB out_w B-fragments
  __shared__ float2 xbuf[OBS_LEN][32];               // 3 KB shifted obs
  __shared__ float  ostage[OBS_LEN][64];             // 3 KB per-chunk out staging

  const int tid = threadIdx.x;
  const int w   = tid >> 6;          // wave 0..7
  const int l   = tid & 63;
  const int p   = (tid >> 4) & 3;
  const int ln  = tid & 15;
  const int wofs = w * 16;           // wave's 16-hd slice
  const bool w7 = (w == 7);

  const int b     = blockIdx.x;      // 256 blocks, 1 per CU
  const int b0    = (b & 63) * 32;
  const int kslot = b >> 6;          // kk = kslot*5 + c

  // ---- shifted obs ----
  if (tid < OBS_LEN*32){
    int t = tid >> 5, cc = tid & 31;
    int st = t ? (t-1) : 0;
    const float* pp = obs + ((size_t)st*BB + b0 + cc)*3;
    xbuf[t][cc] = make_float2(pp[0], pp[1]);
  }
  // ---- out_w fragments -> LDS ----
  if (tid < 256){
    bf16x8 wf;
    if constexpr (FWS){
      wf = *reinterpret_cast<const bf16x8*>(&ws[WSO_OFF + tid*8]);
    } else {
      int q = tid >> 6, ll = tid & 63;
      int lln = ll & 15, pp2 = (ll >> 4) & 3;
      #pragma unroll
      for (int j=0; j<8; ++j)
        wf[j] = (lln < NCQ) ? f2bf(oww[(q*32+pp2*8+j)*NCQ + lln]) : (short)0;
    }
    *reinterpret_cast<bf16x8*>(&ofrag[tid*8]) = wf;
  }
  const float obv = (ln < NCQ) ? obb[ln] : 0.f;

  // ---- w_hh -> register fragments (64 VGPR), coalesced when FWS ----
  bf16x8 wfrag[4][4];
  #pragma unroll
  for (int gate=0; gate<4; ++gate){
    #pragma unroll
    for (int q=0; q<4; ++q){
      if constexpr (FWS){
        wfrag[gate][q] = *reinterpret_cast<const bf16x8*>(
            &ws[WSW_OFF + (((w*4+gate)*4+q)*64 + l)*8]);
      } else {
        int col = gate*128 + wofs + ln;
        const float* s = whh + col*HD + q*32 + p*8;
        float4 f0 = *reinterpret_cast<const float4*>(s);
        float4 f1 = *reinterpret_cast<const float4*>(s+4);
        bf16x8 wf;
        wf[0]=f2bf(f0.x); wf[1]=f2bf(f0.y); wf[2]=f2bf(f0.z); wf[3]=f2bf(f0.w);
        wf[4]=f2bf(f1.x); wf[5]=f2bf(f1.y); wf[6]=f2bf(f1.z); wf[7]=f2bf(f1.w);
        wfrag[gate][q] = wf;
      }
    }
  }
  float wihA[4], wihB[4], biasv[4];
  #pragma unroll
  for (int gate=0; gate<4; ++gate){
    int col = gate*128 + wofs + ln;
    wihA[gate]  = wih[col*2];
    wihB[gate]  = wih[col*2+1];
    biasv[gate] = bih[col] + bhh[col];
  }

  // ---- 5 sequential chunks ----
  #pragma unroll 1
  for (int c=0; c<5; ++c){
    const int kk = kslot*5 + c;

    __syncthreads();                 // WAR on hbuf/abuf/ostage from previous chunk
    // stage h0 -> hbuf[0]
    {
      const float* src = pred + ((size_t)(kk*BB + b0))*HD;
      #pragma unroll
      for (int it=0; it<2; ++it){
        int u = tid + it*512;
        int row = u >> 5, c4 = (u & 31)*4;
        float4 v = *reinterpret_cast<const float4*>(src + row*HD + c4);
        int e = (row*HD + c4) ^ ((row&7)*8);
        *reinterpret_cast<uint32_t*>(&hbuf[0][e])   = pack2(v.x, v.y);
        *reinterpret_cast<uint32_t*>(&hbuf[0][e+2]) = pack2(v.z, v.w);
      }
    }
    __syncthreads();

    // ---- MLP GEMM1: [32,128] @ map_w0 -> [32,256]; 32 cols/wave ----
    {
      f32x4 acc1[2][2];
      #pragma unroll
      for (int ct=0; ct<2; ++ct){
        float mb = mb0[w*32 + ct*16 + ln];
        f32x4 v = {mb,mb,mb,mb};
        acc1[0][ct]=v; acc1[1][ct]=v;
      }
      #pragma unroll
      for (int q=0; q<4; ++q){
        bf16x8 af0 = ldh(hbuf[0], ln, q, p), af1 = ldh(hbuf[0], 16+ln, q, p);
        #pragma unroll
        for (int ct=0; ct<2; ++ct){
          bf16x8 wf;
          if constexpr (FWS){
            wf = *reinterpret_cast<const bf16x8*>(
                &ws[WSM0_OFF + (((w*2+ct)*4+q)*64 + l)*8]);
          } else {
            #pragma unroll
            for (int j=0; j<8; ++j)
              wf[j] = f2bf(mw0[(q*32+p*8+j)*MIDD + (w*32 + ct*16 + ln)]);
          }
          acc1[0][ct] = mm(af0, wf, acc1[0][ct]);
          acc1[1][ct] = mm(af1, wf, acc1[1][ct]);
        }
      }
      #pragma unroll
      for (int rt=0; rt<2; ++rt)
      #pragma unroll
      for (int ct=0; ct<2; ++ct)
      #pragma unroll
      for (int r=0; r<4; ++r){
        float v = acc1[rt][ct][r];
        v = (v>0.f)? v : 0.01f*v;
        int row = rt*16 + p*4 + r;
        abuf[(row*MIDD + w*32 + ct*16 + ln) ^ ((row&7)*8)] = (uint16_t)f2bf(v);
      }
    }
    __syncthreads();                 // abuf ready; hbuf[0] reads done

    // ---- MLP GEMM2: [32,256] @ map_w1 -> h_init -> hbuf[0]; 16 cols/wave ----
    float c_[2][4];
    {
      f32x4 acc2[2];
      float mb = mb1[wofs + ln];
      f32x4 v = {mb,mb,mb,mb};
      acc2[0]=v; acc2[1]=v;
      #pragma unroll
      for (int q=0; q<8; ++q){
        bf16x8 af0 = lda(abuf, ln, q, p), af1 = lda(abuf, 16+ln, q, p);
        bf16x8 wf;
        if constexpr (FWS){
          wf = *reinterpret_cast<const bf16x8*>(&ws[WSM1_OFF + ((w*8+q)*64 + l)*8]);
        } else {
          #pragma unroll
          for (int j=0; j<8; ++j)
            wf[j] = f2bf(mw1[(q*32+p*8+j)*HD + wofs + ln]);
        }
        acc2[0] = mm(af0, wf, acc2[0]);
        acc2[1] = mm(af1, wf, acc2[1]);
      }
      #pragma unroll
      for (int rt=0; rt<2; ++rt)
      #pragma unroll
      for (int r=0; r<4; ++r){
        int row = rt*16 + p*4 + r;
        hbuf[0][(row*HD + wofs + ln) ^ ((row&7)*8)] = (uint16_t)f2bf(acc2[rt][r]);
        c_[rt][r] = 0.f;
      }
    }
    __syncthreads();                 // h_init visible

    // ---- 12 recurrent steps, double-buffered h, ONE barrier/step ----
    #pragma unroll 1
    for (int t=0; t<OBS_LEN; ++t){
      const int cur = t & 1, nxt = cur ^ 1;
      f32x4 acc[2][4];
      #pragma unroll
      for (int rt=0; rt<2; ++rt){
        #pragma unroll
        for (int r=0; r<4; ++r){
          float2 xv = xbuf[t][rt*16 + p*4 + r];
          #pragma unroll
          for (int gate=0; gate<4; ++gate)
            acc[rt][gate][r] = fmaf(xv.x, wihA[gate], fmaf(xv.y, wihB[gate], biasv[gate]));
        }
      }
      f32x4 a8[2];
      if (w7 && t>0){ f32x4 v={obv,obv,obv,obv}; a8[0]=v; a8[1]=v; }
      #pragma unroll
      for (int q=0; q<4; ++q){
        bf16x8 af0 = ldh(hbuf[cur], ln, q, p), af1 = ldh(hbuf[cur], 16+ln, q, p);
        #pragma unroll
        for (int gate=0; gate<4; ++gate){
          acc[0][gate] = mm(af0, wfrag[gate][q], acc[0][gate]);
          acc[1][gate] = mm(af1, wfrag[gate][q], acc[1][gate]);
        }
        if (w7 && t>0){
          bf16x8 of = *reinterpret_cast<const bf16x8*>(&ofrag[(q*64 + l)*8]);
          a8[0] = mm(af0, of, a8[0]);
          a8[1] = mm(af1, of, a8[1]);
        }
      }
      if (w7 && t>0 && ln<NCQ){
        #pragma unroll
        for (int rt=0; rt<2; ++rt)
        #pragma unroll
        for (int r=0; r<4; ++r)
          ostage[t-1][(rt*16 + p*4 + r)*NCQ + ln] = a8[rt][r];   // LDS, no vmcnt
      }
      #pragma unroll
      for (int rt=0; rt<2; ++rt)
      #pragma unroll
      for (int r=0; r<4; ++r){
        float iv = hsig(acc[rt][0][r]);
        float fv = hsig(acc[rt][1][r]);
        float gv = clip1(acc[rt][2][r]);
        float ov = hsig(acc[rt][3][r]);
        float cv = fmaf(fv, c_[rt][r], iv*gv);
        c_[rt][r] = cv;
        int row = rt*16 + p*4 + r;
        hbuf[nxt][(row*HD + wofs + ln) ^ ((row&7)*8)] = (uint16_t)f2bf(ov * clip1(cv));
      }
      __syncthreads();               // h[nxt] visible (WAR on cur is 2 barriers away)
    }

    // ---- final out_11 = h_12 @ out_w + out_b (final h in hbuf[0]) ----
    if (w7){
      f32x4 o0 = {obv,obv,obv,obv}, o1 = o0;
      #pragma unroll
      for (int q=0; q<4; ++q){
        bf16x8 af0 = ldh(hbuf[0], ln, q, p), af1 = ldh(hbuf[0], 16+ln, q, p);
        bf16x8 of = *reinterpret_cast<const bf16x8*>(&ofrag[(q*64 + l)*8]);
        o0 = mm(af0, of, o0);
        o1 = mm(af1, of, o1);
      }
      if (ln < NCQ){
        #pragma unroll
        for (int r=0; r<4; ++r){
          ostage[11][(     p*4 + r)*NCQ + ln] = o0[r];
          ostage[11][(16 + p*4 + r)*NCQ + ln] = o1[r];
        }
      }
    }
    __syncthreads();                 // ostage complete

    // ---- one coalesced cooperative store per chunk (single vmcnt drain) ----
    for (int u = tid; u < OBS_LEN*64; u += 512){
      int t = u >> 6, e = u & 63;
      outp[((size_t)(t*KS + kk)*BB + b0)*NCQ + e] = ostage[t][e];
    }
  }
}

extern "C" void kernel_launch(void* const* d_in, const int* in_sizes, int n_in,
                              void* d_out, int out_size, void* d_ws, size_t ws_size,
                              hipStream_t stream) {
  (void)in_sizes; (void)n_in; (void)out_size;
  const float* obs  = (const float*)d_in[0];
  const float* pred = (const float*)d_in[1];
  const float* mw0  = (const float*)d_in[2];
  const float* mb0  = (const float*)d_in[3];
  const float* mw1  = (const float*)d_in[4];
  const float* mb1  = (const float*)d_in[5];
  const float* wih  = (const float*)d_in[6];
  const float* whh  = (const float*)d_in[7];
  const float* bih  = (const float*)d_in[8];
  const float* bhh  = (const float*)d_in[9];
  const float* oww  = (const float*)d_in[10];
  const float* obb  = (const float*)d_in[11];
  float* outp = (float*)d_out;

  if (ws_size >= (size_t)WS_ELEMS * sizeof(uint16_t)){
    uint16_t* ws = (uint16_t*)d_ws;
    CRMF_prep_kernel<<<dim3(65), dim3(256), 0, stream>>>(mw0, mw1, whh, oww, ws);
    CRMF_35296041239144_kernel<true><<<dim3(256), dim3(512), 0, stream>>>(
        obs, pred, mw0, mb0, mw1, mb1, wih, whh, bih, bhh, oww, obb,
        (const uint16_t*)ws, outp);
  } else {
    CRMF_35296041239144_kernel<false><<<dim3(256), dim3(512), 0, stream>>>(
        obs, pred, mw0, mb0, mw1, mb1, wih, whh, bih, bhh, oww, obb,
        (const uint16_t*)nullptr, outp);
  }
}